// Round 4
// baseline (1617.839 us; speedup 1.0000x reference)
//
#include <hip/hip_runtime.h>
#include <stdint.h>

namespace {
constexpr int Wd = 960, Hd = 544, Cd = 16, Id = 5, Bd = 2;
constexpr int HW = Hd * Wd;                       // 522240
constexpr long CHW = (long)Cd * HW;               // 8,355,840
constexpr long FRAME_BSTRIDE = (long)Id * CHW;
constexpr long FLOW_BSTRIDE  = (long)Id * 2 * HW;

constexpr int TSX = 64, TSY = 32;   // output tile
constexpr int HALO = 12;            // 3 sigma of 4px flow; tails -> fallback
constexpr int TWX = TSX + 2 * HALO; // 88 (multiple of 4: GLL groups never straddle rows)
constexpr int TWY = TSY + 2 * HALO; // 56
constexpr int TILE_PAD = 5120;      // 20 chunks x 256 floats >= 88*56=4928
constexpr int GX = Wd / TSX;        // 15
constexpr int GY = Hd / TSY;        // 17
constexpr int NWG = GX * GY * Bd;   // 510
}

struct F2 { float x, y; };  // 4-aligned pair -> ds_read2_b32

__global__ __launch_bounds__(256, 4) void warp_tile_kernel(
    const float* __restrict__ src, float* __restrict__ dst,
    const float* __restrict__ flow)
{
  __shared__ float tile[2][TILE_PAD];   // 40 KB -> 4 blocks/CU

  // XCD-aware bijective swizzle (m204): contiguous wgid chunk per XCD.
  const int orig = blockIdx.x;
  const int xcd  = orig & 7;
  constexpr int q = NWG / 8, r = NWG % 8;  // 63, 6
  const int wgid = (xcd < r ? xcd * (q + 1) : r * (q + 1) + (xcd - r) * q)
                 + (orig >> 3);

  const int b   = wgid / (GX * GY);
  const int rem = wgid - b * (GX * GY);
  const int tyb = rem / GX;
  const int txb = rem - tyb * GX;
  const int X0 = txb * TSX;
  const int Y0 = tyb * TSY;

  const float* srcF = src + (long)b * FRAME_BSTRIDE;
  float*       dstF = dst + (long)b * FRAME_BSTRIDE;
  const float* fl   = flow + (long)b * FLOW_BSTRIDE;

  // Thread -> 8 px: rows y0,y0+16; 4 consecutive x (float4 granularity).
  const int t   = threadIdx.x;
  const int x   = X0 + ((t & 15) << 2);
  const int y0  = Y0 + (t >> 4);
  const int y1  = y0 + 16;
  const int pix0 = y0 * Wd + x;
  const int pix1 = y1 * Wd + x;

  float4 fxa = *reinterpret_cast<const float4*>(fl + pix0);
  float4 fya = *reinterpret_cast<const float4*>(fl + HW + pix0);
  float4 fxb = *reinterpret_cast<const float4*>(fl + pix1);
  float4 fyb = *reinterpret_cast<const float4*>(fl + HW + pix1);

  float w00[8], w10[8], w01[8], w11[8];
  int   lA[8];          // LDS byte offset of corner00, or -1 -> global fallback
  uint32_t pxy[8];      // packed (ix0+128, iy0+128) for fallback

#pragma unroll
  for (int j = 0; j < 8; ++j) {
    const int e = j & 3;
    const bool hi = j >= 4;
    float fx = hi ? ((e==0)?fxb.x:(e==1)?fxb.y:(e==2)?fxb.z:fxb.w)
                  : ((e==0)?fxa.x:(e==1)?fxa.y:(e==2)?fxa.z:fxa.w);
    float fy = hi ? ((e==0)?fyb.x:(e==1)?fyb.y:(e==2)?fyb.z:fyb.w)
                  : ((e==0)?fya.x:(e==1)?fya.y:(e==2)?fya.z:fya.w);
    float gx = (float)(x + e) + fx;
    float gy = (float)(hi ? y1 : y0) + fy;
    float x0f = floorf(gx), y0f = floorf(gy);
    float wx = gx - x0f, wy = gy - y0f;
    bool vx0 = (x0f >= 0.f) && (x0f <= (float)(Wd - 1));
    bool vx1 = (x0f + 1.f >= 0.f) && (x0f + 1.f <= (float)(Wd - 1));
    bool vy0 = (y0f >= 0.f) && (y0f <= (float)(Hd - 1));
    bool vy1 = (y0f + 1.f >= 0.f) && (y0f + 1.f <= (float)(Hd - 1));
    w00[j] = (1.f - wx) * (1.f - wy) * ((vx0 && vy0) ? 1.f : 0.f);
    w10[j] = wx * (1.f - wy)         * ((vx1 && vy0) ? 1.f : 0.f);
    w01[j] = (1.f - wx) * wy         * ((vx0 && vy1) ? 1.f : 0.f);
    w11[j] = wx * wy                 * ((vx1 && vy1) ? 1.f : 0.f);
    int ix0 = (int)x0f;
    int iy0 = (int)y0f;
    int lx = ix0 - (X0 - HALO);
    int ly = iy0 - (Y0 - HALO);
    bool ft = (lx >= 0) & (lx <= TWX - 2) & (ly >= 0) & (ly <= TWY - 2);
    lA[j] = ft ? (ly * TWX + lx) * 4 : -1;
    uint32_t px_ = (uint32_t)min(max(ix0 + 128, 0), 65535);
    uint32_t py_ = (uint32_t)min(max(iy0 + 128, 0), 65535);
    pxy[j] = px_ | (py_ << 16);
  }

  // Fill plumbing: buffer = 20 chunks of 1 KB; wave wv owns chunks wv+4k.
  // Global source per (lane, chunk) fixed across channels -> precompute once.
  const int lane = t & 63;
  const int wv   = t >> 6;
  int goff[5];
#pragma unroll
  for (int k = 0; k < 5; ++k) {
    int foff = (wv + 4 * k) * 256 + lane * 4;   // float index in tile
    int ly = foff / TWX;                        // const-div -> magic mul
    int lx = foff - ly * TWX;
    int gx = min(max(X0 - HALO + lx, 0), Wd - 4);  // clamped cells only feed w=0
    int gy = min(max(Y0 - HALO + ly, 0), Hd - 1);
    goff[k] = gy * Wd + gx;
  }

  auto fill = [&](int nb, int c) {
    const float* sC = srcF + (long)c * HW;
#pragma unroll
    for (int k = 0; k < 5; ++k) {
      __builtin_amdgcn_global_load_lds(
          (__attribute__((address_space(1))) void*)(void*)(sC + goff[k]),
          (__attribute__((address_space(3))) void*)&tile[nb][(wv + 4 * k) * 256],
          16, 0, 0);
    }
  };

  fill(0, 0);

#pragma unroll 2
  for (int c = 0; c < Cd; ++c) {
    __syncthreads();                        // buf[c&1] ready; prior reads done
    if (c + 1 < Cd) fill((c + 1) & 1, c + 1);
    const float* sC = srcF + (long)c * HW;
    const float* tb = tile[c & 1];
    float ov[8];
#pragma unroll
    for (int j = 0; j < 8; ++j) {
      float v;
      if (lA[j] >= 0) {
        F2 r0 = *(const F2*)((const char*)tb + lA[j]);
        F2 r1 = *(const F2*)((const char*)tb + lA[j] + TWX * 4);
        v = (w00[j] * r0.x + w10[j] * r0.y) + (w01[j] * r1.x + w11[j] * r1.y);
      } else {
        uint32_t p = pxy[j];
        int ix0 = (int)(p & 0xffffu) - 128;
        int iy0 = (int)(p >> 16) - 128;
        int xc0 = min(max(ix0, 0), Wd - 1), xc1 = min(max(ix0 + 1, 0), Wd - 1);
        int yc0 = min(max(iy0, 0), Hd - 1), yc1 = min(max(iy0 + 1, 0), Hd - 1);
        v = w00[j] * sC[yc0 * Wd + xc0] + w10[j] * sC[yc0 * Wd + xc1]
          + w01[j] * sC[yc1 * Wd + xc0] + w11[j] * sC[yc1 * Wd + xc1];
      }
      ov[j] = v;
    }
    float4 o0 = make_float4(ov[0], ov[1], ov[2], ov[3]);
    float4 o1 = make_float4(ov[4], ov[5], ov[6], ov[7]);
    *reinterpret_cast<float4*>(dstF + (long)c * HW + pix0) = o0;
    *reinterpret_cast<float4*>(dstF + (long)c * HW + pix1) = o1;
  }
}

extern "C" void kernel_launch(void* const* d_in, const int* in_sizes, int n_in,
                              void* d_out, int out_size, void* d_ws, size_t ws_size,
                              hipStream_t stream) {
  const float* feat = (const float*)d_in[0];
  const float* mv   = (const float*)d_in[1];
  float*       out  = (float*)d_out;

  dim3 block(256, 1, 1);
  dim3 grid(NWG, 1, 1);   // 510 blocks, b/tile decoded in-kernel (swizzled)

  // Scratch = frame-0 slot of d_out (frame 0 is written last, by plain copy).
  float* S = out;

  auto warp = [&](const float* src, float* dst, int j) {
    warp_tile_kernel<<<grid, block, 0, stream>>>(src, dst, mv + (long)j * 2 * HW);
  };

  // frame 1: mv0
  warp(feat + 1 * CHW, out + 1 * CHW, 0);
  // frame 2: mv1, mv0  (even chain: start in scratch)
  warp(feat + 2 * CHW, S, 1);
  warp(S, out + 2 * CHW, 0);
  // frame 3: mv2, mv1, mv0  (odd chain: start in own slot)
  warp(feat + 3 * CHW, out + 3 * CHW, 2);
  warp(out + 3 * CHW, S, 1);
  warp(S, out + 3 * CHW, 0);
  // frame 4: mv3, mv2, mv1, mv0  (even chain)
  warp(feat + 4 * CHW, S, 3);
  warp(S, out + 4 * CHW, 2);
  warp(out + 4 * CHW, S, 1);
  warp(S, out + 4 * CHW, 0);

  // frame 0: plain copy (after all scratch uses of the frame-0 slot).
  for (int b = 0; b < Bd; ++b) {
    hipMemcpyAsync(out + (long)b * FRAME_BSTRIDE,
                   feat + (long)b * FRAME_BSTRIDE,
                   CHW * sizeof(float), hipMemcpyDeviceToDevice, stream);
  }
}

// Round 5
// 383.734 us; speedup vs baseline: 4.2160x; 4.2160x over previous
//
#include <hip/hip_runtime.h>
#include <stdint.h>

namespace {
constexpr int Wd = 960, Hd = 544, Cd = 16, Id = 5, Bd = 2;
constexpr int HW = Hd * Wd;                       // 522240
constexpr long CHW = (long)Cd * HW;               // 8,355,840
constexpr long FRAME_BSTRIDE = (long)Id * CHW;
constexpr long FLOW_BSTRIDE  = (long)Id * 2 * HW;

constexpr int TSX = 64, TSY = 32;   // output tile, 512 thr x 4 px
constexpr int HALO = 12;            // 3 sigma of 4px flow; tails -> global fallback
constexpr int TWX = TSX + 2 * HALO; // 88 (mult of 4: 16B fill groups never straddle rows)
constexpr int TWY = TSY + 2 * HALO; // 56
constexpr int TILE_FLOATS = TWX * TWY;        // 4928
constexpr int NCHUNK = 20;                    // 20 x 256 floats = 5120 >= 4928
constexpr int TILE_PAD = NCHUNK * 256 + 264;  // pad: row 58 reads stay in-bounds
constexpr int GX = Wd / TSX;        // 15
constexpr int GY = Hd / TSY;        // 17
constexpr int NWG = GX * GY * Bd;   // 510
}

struct F2 { float x, y; };  // 4-aligned pair -> paired LDS read

__global__ __launch_bounds__(512) void warp_tile_kernel(
    const float* __restrict__ src, float* __restrict__ dst,
    const float* __restrict__ flow)
{
  __shared__ float tile[2][TILE_PAD];   // ~41 KB

  // XCD-aware bijective swizzle (m204): contiguous wgid chunk per XCD.
  const int orig = blockIdx.x;
  const int xcd  = orig & 7;
  constexpr int q = NWG / 8, r = NWG % 8;  // 63, 6
  const int wgid = (xcd < r ? xcd * (q + 1) : r * (q + 1) + (xcd - r) * q)
                 + (orig >> 3);

  const int b   = wgid / (GX * GY);
  const int rem = wgid - b * (GX * GY);
  const int tyb = rem / GX;
  const int txb = rem - tyb * GX;
  const int X0 = txb * TSX;
  const int Y0 = tyb * TSY;

  const float* srcF = src + (long)b * FRAME_BSTRIDE;
  float*       dstF = dst + (long)b * FRAME_BSTRIDE;
  const float* fl   = flow + (long)b * FLOW_BSTRIDE;

  // Thread -> 4 consecutive x px, one row. 512 thr = 64x32 tile.
  const int t   = threadIdx.x;
  const int x   = X0 + ((t & 15) << 2);
  const int y   = Y0 + (t >> 4);
  const int pix = y * Wd + x;

  float4 fxv = *reinterpret_cast<const float4*>(fl + pix);
  float4 fyv = *reinterpret_cast<const float4*>(fl + HW + pix);

  float w00[4], w10[4], w01[4], w11[4];
  int   lA[4];                       // LDS byte addr of corner00, or -1
  int   g00[4], g10[4], g01[4], g11[4];

#pragma unroll
  for (int j = 0; j < 4; ++j) {
    float fx = (j == 0) ? fxv.x : (j == 1) ? fxv.y : (j == 2) ? fxv.z : fxv.w;
    float fy = (j == 0) ? fyv.x : (j == 1) ? fyv.y : (j == 2) ? fyv.z : fyv.w;
    float gx = (float)(x + j) + fx;
    float gy = (float)y + fy;
    float x0f = floorf(gx), y0f = floorf(gy);
    float wx = gx - x0f, wy = gy - y0f;
    bool vx0 = (x0f >= 0.f) && (x0f <= (float)(Wd - 1));
    bool vx1 = (x0f + 1.f >= 0.f) && (x0f + 1.f <= (float)(Wd - 1));
    bool vy0 = (y0f >= 0.f) && (y0f <= (float)(Hd - 1));
    bool vy1 = (y0f + 1.f >= 0.f) && (y0f + 1.f <= (float)(Hd - 1));
    w00[j] = (1.f - wx) * (1.f - wy) * ((vx0 && vy0) ? 1.f : 0.f);
    w10[j] = wx * (1.f - wy)         * ((vx1 && vy0) ? 1.f : 0.f);
    w01[j] = (1.f - wx) * wy         * ((vx0 && vy1) ? 1.f : 0.f);
    w11[j] = wx * wy                 * ((vx1 && vy1) ? 1.f : 0.f);
    int ix0 = (int)x0f;
    int iy0 = (int)y0f;
    int lx = ix0 - (X0 - HALO);
    int ly = iy0 - (Y0 - HALO);
    bool ft = (lx >= 0) & (lx <= TWX - 2) & (ly >= 0) & (ly <= TWY - 2);
    lA[j] = ft ? (ly * TWX + lx) * 4 : -1;
    int xc0 = min(max(ix0, 0), Wd - 1), xc1 = min(max(ix0 + 1, 0), Wd - 1);
    int yc0 = min(max(iy0, 0), Hd - 1), yc1 = min(max(iy0 + 1, 0), Hd - 1);
    g00[j] = yc0 * Wd + xc0;
    g10[j] = yc0 * Wd + xc1;
    g01[j] = yc1 * Wd + xc0;
    g11[j] = yc1 * Wd + xc1;
  }

  // Fill plumbing: 20 chunks of 256 floats (1 KB). Wave wv owns chunks
  // {wv, wv+8, wv+16<20}. Global srcs fixed across channels -> precompute.
  const int lane = t & 63;
  const int wv   = t >> 6;
  const int nck  = (wv < 4) ? 3 : 2;
  int goff[3];
#pragma unroll
  for (int k = 0; k < 3; ++k) {
    int ck = wv + 8 * k;
    if (ck < NCHUNK) {
      int foff = ck * 256 + lane * 4;             // float index in tile
      int ly = foff / TWX;
      int lx = foff - ly * TWX;
      int gxc = min(max(X0 - HALO + lx, 0), Wd - 4);  // clamped cells feed w=0 only
      int gyc = min(max(Y0 - HALO + ly, 0), Hd - 1);
      goff[k] = gyc * Wd + gxc;
    }
  }

  auto fill = [&](int nb, int c) {
    const float* sC = srcF + (long)c * HW;
#pragma unroll
    for (int k = 0; k < 3; ++k) {
      if (k < nck) {
        __builtin_amdgcn_global_load_lds(
            (__attribute__((address_space(1))) void*)(void*)(sC + goff[k]),
            (__attribute__((address_space(3))) void*)&tile[nb][(wv + 8 * k) * 256],
            16, 0, 0);
      }
    }
  };

  fill(0, 0);

#pragma unroll
  for (int c = 0; c < Cd; ++c) {
    __syncthreads();                        // buf[c&1] ready; prior reads done
    if (c + 1 < Cd) fill((c + 1) & 1, c + 1);
    const float* sC = srcF + (long)c * HW;
    const float* tb = tile[c & 1];
    float ov[4];
#pragma unroll
    for (int j = 0; j < 4; ++j) {
      float v;
      if (lA[j] >= 0) {
        F2 r0 = *(const F2*)((const char*)tb + lA[j]);
        F2 r1 = *(const F2*)((const char*)tb + lA[j] + TWX * 4);
        v = (w00[j] * r0.x + w10[j] * r0.y) + (w01[j] * r1.x + w11[j] * r1.y);
      } else {
        v = w00[j] * sC[g00[j]] + w10[j] * sC[g10[j]]
          + w01[j] * sC[g01[j]] + w11[j] * sC[g11[j]];
      }
      ov[j] = v;
    }
    *reinterpret_cast<float4*>(dstF + (long)c * HW + pix)
        = make_float4(ov[0], ov[1], ov[2], ov[3]);
  }
}

extern "C" void kernel_launch(void* const* d_in, const int* in_sizes, int n_in,
                              void* d_out, int out_size, void* d_ws, size_t ws_size,
                              hipStream_t stream) {
  const float* feat = (const float*)d_in[0];
  const float* mv   = (const float*)d_in[1];
  float*       out  = (float*)d_out;

  dim3 block(512, 1, 1);
  dim3 grid(NWG, 1, 1);   // 510 blocks, b/tile decoded in-kernel (swizzled)

  // Scratch = frame-0 slot of d_out (frame 0 is written last, by plain copy).
  float* S = out;

  auto warp = [&](const float* src, float* dst, int j) {
    warp_tile_kernel<<<grid, block, 0, stream>>>(src, dst, mv + (long)j * 2 * HW);
  };

  // frame 1: mv0
  warp(feat + 1 * CHW, out + 1 * CHW, 0);
  // frame 2: mv1, mv0  (even chain: start in scratch)
  warp(feat + 2 * CHW, S, 1);
  warp(S, out + 2 * CHW, 0);
  // frame 3: mv2, mv1, mv0  (odd chain: start in own slot)
  warp(feat + 3 * CHW, out + 3 * CHW, 2);
  warp(out + 3 * CHW, S, 1);
  warp(S, out + 3 * CHW, 0);
  // frame 4: mv3, mv2, mv1, mv0  (even chain)
  warp(feat + 4 * CHW, S, 3);
  warp(S, out + 4 * CHW, 2);
  warp(out + 4 * CHW, S, 1);
  warp(S, out + 4 * CHW, 0);

  // frame 0: plain copy (after all scratch uses of the frame-0 slot).
  for (int b = 0; b < Bd; ++b) {
    hipMemcpyAsync(out + (long)b * FRAME_BSTRIDE,
                   feat + (long)b * FRAME_BSTRIDE,
                   CHW * sizeof(float), hipMemcpyDeviceToDevice, stream);
  }
}